// Round 1
// baseline (99.189 us; speedup 1.0000x reference)
//
#include <hip/hip_runtime.h>

// Problem constants (match reference)
#define D_DIM 160
#define H_DIM 192
#define W_DIM 224
#define VPT 8            // voxels per thread (divides W_DIM; keeps rows unwrapped)
#define BLOCK 256

// out[b,d,h,w,i] = sum_j (A[b,i,j] - delta_ij) * mesh_j + t[b,i]
// mesh = (d - 79.5, h - 95.5, w - 111.5)
__global__ __launch_bounds__(BLOCK) void AffineToDenseShift_kernel(
    const float* __restrict__ matrix, float* __restrict__ out) {
  const int b = blockIdx.y;
  const float* M = matrix + b * 12;  // uniform address -> scalar loads

  float a00 = M[0] - 1.0f, a01 = M[1],       a02 = M[2],        t0 = M[3];
  float a10 = M[4],        a11 = M[5] - 1.0f, a12 = M[6],        t1 = M[7];
  float a20 = M[8],        a21 = M[9],        a22 = M[10] - 1.0f, t2 = M[11];

  const long long per_batch = (long long)D_DIM * H_DIM * W_DIM;  // 6,881,280
  const long long v0 = ((long long)blockIdx.x * BLOCK + threadIdx.x) * VPT;
  if (v0 >= per_batch) return;

  const int iv = (int)v0;
  const int w  = iv % W_DIM;
  const int t2d = iv / W_DIM;
  const int h  = t2d % H_DIM;
  const int d  = t2d / H_DIM;

  const float md = (float)d - (float)(D_DIM - 1) * 0.5f;
  const float mh = (float)h - (float)(H_DIM - 1) * 0.5f;
  const float mw = (float)w - (float)(W_DIM - 1) * 0.5f;

  // voxel 0 values
  float x = a00 * md + a01 * mh + a02 * mw + t0;
  float y = a10 * md + a11 * mh + a12 * mw + t1;
  float z = a20 * md + a21 * mh + a22 * mw + t2;

  float4* __restrict__ dst = (float4*)(out + ((long long)b * per_batch + v0) * 3);

  #pragma unroll
  for (int g = 0; g < VPT / 4; ++g) {
    // 4 voxels -> 12 floats -> 3 float4 stores, all-register
    float4 f0, f1, f2;
    f0.x = x; f0.y = y; f0.z = z;
    x += a02; y += a12; z += a22;
    f0.w = x; f1.x = y; f1.y = z;
    x += a02; y += a12; z += a22;
    f1.z = x; f1.w = y; f2.x = z;
    x += a02; y += a12; z += a22;
    f2.y = x; f2.z = y; f2.w = z;
    x += a02; y += a12; z += a22;
    dst[g * 3 + 0] = f0;
    dst[g * 3 + 1] = f1;
    dst[g * 3 + 2] = f2;
  }
}

extern "C" void kernel_launch(void* const* d_in, const int* in_sizes, int n_in,
                              void* d_out, int out_size, void* d_ws, size_t ws_size,
                              hipStream_t stream) {
  const float* matrix = (const float*)d_in[0];
  float* out = (float*)d_out;

  const int batch = in_sizes[0] / 12;                       // [B,3,4] fp32
  const long long per_batch = (long long)D_DIM * H_DIM * W_DIM;
  const int blocks_x = (int)((per_batch + (long long)BLOCK * VPT - 1) /
                             ((long long)BLOCK * VPT));     // 3360, exact

  dim3 grid(blocks_x, batch);
  AffineToDenseShift_kernel<<<grid, BLOCK, 0, stream>>>(matrix, out);
}

// Round 2
// 61.634 us; speedup vs baseline: 1.6093x; 1.6093x over previous
//
#include <hip/hip_runtime.h>

// Problem constants (match reference)
#define D_DIM 160
#define H_DIM 192
#define W_DIM 224
#define BLOCK 256
#define F4PT 6   // float4 per thread; block covers 256*6 = 1536 float4 = 2048 voxels

// out[b,d,h,w,i] = sum_j (A[b,i,j] - delta_ij) * mesh_j + t[b,i]
// mesh = (d - 79.5, h - 95.5, w - 111.5)
//
// Stores are wave-unit-stride: thread writes float4 index f = base + tid + 256k,
// so each store instruction is 64 lanes x 16B fully contiguous (1 KB/instr).
// A float4 spans voxels v and v+1 (3 floats/voxel); phase p = (4f) mod 3 picks
// the packing via cndmask.
__global__ __launch_bounds__(BLOCK) void AffineToDenseShift_kernel(
    const float* __restrict__ matrix, float* __restrict__ out) {
  const int b = blockIdx.y;
  const float* M = matrix + b * 12;  // wave-uniform -> scalar loads

  const float a00 = M[0] - 1.0f, a01 = M[1],        a02 = M[2],         t0 = M[3];
  const float a10 = M[4],        a11 = M[5] - 1.0f, a12 = M[6],         t1 = M[7];
  const float a20 = M[8],        a21 = M[9],        a22 = M[10] - 1.0f, t2 = M[11];

  const long long batch_floats = (long long)D_DIM * H_DIM * W_DIM * 3;  // 20,643,840
  float4* __restrict__ dst = (float4*)(out + (long long)b * batch_floats);

  const unsigned fbase = blockIdx.x * (BLOCK * F4PT) + threadIdx.x;

  #pragma unroll
  for (int k = 0; k < F4PT; ++k) {
    const unsigned f = fbase + (unsigned)k * BLOCK;  // float4 index within batch
    const unsigned L = 4u * f;                       // first float index
    const unsigned v = L / 3u;                       // voxel index (magic-mul div)
    const unsigned p = L - 3u * v;                   // phase 0/1/2

    const unsigned w = v % (unsigned)W_DIM;
    const unsigned r = v / (unsigned)W_DIM;
    const unsigned h = r % (unsigned)H_DIM;
    const unsigned d = r / (unsigned)H_DIM;

    const float md = (float)d - (float)(D_DIM - 1) * 0.5f;
    const float mh = (float)h - (float)(H_DIM - 1) * 0.5f;
    const float mw = (float)w - (float)(W_DIM - 1) * 0.5f;

    // voxel v
    const float x0 = fmaf(a00, md, fmaf(a01, mh, fmaf(a02, mw, t0)));
    const float y0 = fmaf(a10, md, fmaf(a11, mh, fmaf(a12, mw, t1)));
    const float z0 = fmaf(a20, md, fmaf(a21, mh, fmaf(a22, mw, t2)));

    // voxel v+1 coords (carry through W then H)
    const bool ww = (w == (unsigned)(W_DIM - 1));
    const bool hw = ww && (h == (unsigned)(H_DIM - 1));
    const float mw1 = ww ? -(float)(W_DIM - 1) * 0.5f : mw + 1.0f;
    const float mh1 = hw ? -(float)(H_DIM - 1) * 0.5f : (ww ? mh + 1.0f : mh);
    const float md1 = hw ? md + 1.0f : md;

    const float x1 = fmaf(a00, md1, fmaf(a01, mh1, fmaf(a02, mw1, t0)));
    const float y1 = fmaf(a10, md1, fmaf(a11, mh1, fmaf(a12, mw1, t1)));
    const float z1 = fmaf(a20, md1, fmaf(a21, mh1, fmaf(a22, mw1, t2)));

    float4 o;
    o.x = (p == 0u) ? x0 : ((p == 1u) ? y0 : z0);
    o.y = (p == 0u) ? y0 : ((p == 1u) ? z0 : x1);
    o.z = (p == 0u) ? z0 : ((p == 1u) ? x1 : y1);
    o.w = (p == 0u) ? x1 : ((p == 1u) ? y1 : z1);
    dst[f] = o;
  }
}

extern "C" void kernel_launch(void* const* d_in, const int* in_sizes, int n_in,
                              void* d_out, int out_size, void* d_ws, size_t ws_size,
                              hipStream_t stream) {
  const float* matrix = (const float*)d_in[0];
  float* out = (float*)d_out;

  const int batch = in_sizes[0] / 12;  // [B,3,4] fp32
  const long long batch_f4 = (long long)D_DIM * H_DIM * W_DIM * 3 / 4;  // 5,160,960
  const int blocks_x = (int)((batch_f4 + (long long)BLOCK * F4PT - 1) /
                             ((long long)BLOCK * F4PT));                // 3360, exact

  dim3 grid(blocks_x, batch);
  AffineToDenseShift_kernel<<<grid, BLOCK, 0, stream>>>(matrix, out);
}